// Round 1
// baseline (364.767 us; speedup 1.0000x reference)
//
#include <hip/hip_runtime.h>

// Problem: B=4, M_IN=16, M_OUT=32, C=32
// x: (B, M_IN, C, C, C, C) fp32, 67,108,864 elements = 256 MiB
// out[b,n,i,c] = sum_m s_i[b,m,c] * W[m,n],  W = alpha+beta+gamma+delta
//   s_0 = s_1 = x.sum(axes 3,4,5)  (keeps c2)
//   s_2       = x.sum(axes 2,4,5)  (keeps c3)
//   s_3       = x.sum(axes 2,3,5)  (keeps c4)
//
// ws layout (floats): s1[64*32] | s3[64*32] | s4[64*32]  = 6144 floats (24 KB)

__global__ __launch_bounds__(256) void zero_k(float* __restrict__ ws) {
    int i = blockIdx.x * 256 + threadIdx.x;
    if (i < 6144) ws[i] = 0.0f;
}

__global__ __launch_bounds__(256) void reduce_k(const float* __restrict__ x,
                                                float* __restrict__ ws) {
    const int t   = threadIdx.x;        // 0..255
    const int bid = blockIdx.x;         // (bm<<5) | c2 ; bm = b*16+m
    const int bm  = bid >> 5;
    const int lane = t & 63;
    const int wv   = t >> 6;            // wave id 0..3

    __shared__ float lds3[4][32];       // per-wave, per-c3 partial
    __shared__ float lds4[32];          // per-c4 partial (one group of 8 per c4)
    __shared__ float lds1[4];           // per-wave total

    // Slab of 32768 contiguous floats = 8192 float4s for this (b,m,c2)
    const float4* xv = (const float4*)x + (size_t)bid * 8192;

    float total = 0.0f;
    #pragma unroll
    for (int it = 0; it < 32; ++it) {   // it == c3 (block-uniform)
        // coalesced: per iteration the block reads 4 KiB contiguous
        float4 v = xv[it * 256 + t];
        float s = (v.x + v.y) + (v.z + v.w);
        total += s;
        // wave-wide butterfly reduce of s -> s3 contribution for c3=it
        #pragma unroll
        for (int off = 1; off < 64; off <<= 1)
            s += __shfl_xor(s, off, 64);
        if (lane == 0) lds3[wv][it] = s;
    }

    // s4: c4 = t>>3 is fixed per thread; reduce total over each group of 8 lanes
    float g = total;
    g += __shfl_xor(g, 1, 64);
    g += __shfl_xor(g, 2, 64);
    g += __shfl_xor(g, 4, 64);
    if ((t & 7) == 0) lds4[t >> 3] = g;   // exactly one writer per c4 in the block

    // s1: continue to full-wave total
    float wsum = g;
    wsum += __shfl_xor(wsum, 8, 64);
    wsum += __shfl_xor(wsum, 16, 64);
    wsum += __shfl_xor(wsum, 32, 64);
    if (lane == 0) lds1[wv] = wsum;

    __syncthreads();

    float* s1 = ws;
    float* s3 = ws + 2048;
    float* s4 = ws + 4096;
    if (t < 32) {
        float v3 = lds3[0][t] + lds3[1][t] + lds3[2][t] + lds3[3][t];
        atomicAdd(&s3[bm * 32 + t], v3);
        atomicAdd(&s4[bm * 32 + t], lds4[t]);
    }
    if (t == 0) {
        // this block exclusively owns s1[bid] -> plain store
        s1[bid] = lds1[0] + lds1[1] + lds1[2] + lds1[3];
    }
}

__global__ __launch_bounds__(256) void finalize_k(const float* __restrict__ ws,
                                                  const float* __restrict__ alpha,
                                                  const float* __restrict__ beta,
                                                  const float* __restrict__ gamma,
                                                  const float* __restrict__ delta,
                                                  float* __restrict__ out) {
    __shared__ float W[512];            // W[m*32+n] = sum of the 4 weight mats
    const int t = threadIdx.x;
    #pragma unroll
    for (int i = t; i < 512; i += 256)
        W[i] = alpha[i] + beta[i] + gamma[i] + delta[i];
    __syncthreads();

    int gid = blockIdx.x * 256 + t;     // 0..16383
    int c  = gid & 31;
    int i4 = (gid >> 5) & 3;
    int n  = (gid >> 7) & 31;
    int b  = gid >> 12;

    const float* s = ws + (i4 <= 1 ? 0 : (i4 == 2 ? 2048 : 4096));
    float acc = 0.0f;
    #pragma unroll
    for (int m = 0; m < 16; ++m)
        acc += s[(b * 16 + m) * 32 + c] * W[m * 32 + n];
    out[gid] = acc;
}

extern "C" void kernel_launch(void* const* d_in, const int* in_sizes, int n_in,
                              void* d_out, int out_size, void* d_ws, size_t ws_size,
                              hipStream_t stream) {
    const float* x     = (const float*)d_in[0];
    const float* alpha = (const float*)d_in[1];
    const float* beta  = (const float*)d_in[2];
    const float* gamma = (const float*)d_in[3];
    const float* delta = (const float*)d_in[4];
    float* out = (float*)d_out;
    float* ws  = (float*)d_ws;

    zero_k<<<24, 256, 0, stream>>>(ws);                       // 6144 floats
    reduce_k<<<2048, 256, 0, stream>>>(x, ws);                // streaming pass
    finalize_k<<<64, 256, 0, stream>>>(ws, alpha, beta, gamma, delta, out);
}